// Round 7
// baseline (316.274 us; speedup 1.0000x reference)
//
#include <hip/hip_runtime.h>

#define B_    16
#define CIN_  128
#define COUT_ 128
#define N_    4096
#define K_    16

typedef __attribute__((ext_vector_type(8))) short bf16x8;  // 8 bf16 = 4 VGPR
typedef __attribute__((ext_vector_type(4))) float f32x4;
typedef __attribute__((ext_vector_type(4))) int   i32x4;

__device__ inline unsigned short f2bf(float f) {  // round-to-nearest-even
  unsigned u = __float_as_uint(f);
  u += 0x7fffu + ((u >> 16) & 1u);
  return (unsigned short)(u >> 16);
}

// XCD-affinity: dispatch is round-robin over 8 XCDs by linear block id, so
// batch b is pinned to XCD b>>1 in BOTH kernels -> gemm produces h[b] into the
// same XCD L2 (4 MB = two 2 MB bf16 slabs) that aggr gathers from.
// ---------------------------------------------------------------------------
// Kernel 1: h[b][n][co] = bf16(relu(sum_ci W[co][ci]*x[b][ci][n]))
// 1024 blocks x 256 thr; tile 64n x 128co, full K=128; wave w owns 16 n.
// x loads issued FIRST so HBM traffic overlaps the W staging + convert.
// W: fp32 global -> bf16 LDS (+8 pad rows -> conflict-free b128 reads).
// ---------------------------------------------------------------------------
__global__ __launch_bounds__(256, 4) void gemm_relu_k(
    const float* __restrict__ x, const float* __restrict__ W,
    unsigned short* __restrict__ h) {
  __shared__ unsigned short Wl[128 * 136];  // [co][ci], +8 pad
  const int tid = threadIdx.x;
  const int l   = blockIdx.x;
  const int b   = ((l & 7) << 1) | ((l >> 3) >> 6);
  const int n0  = ((l >> 3) & 63) * 64;

  const int lane = tid & 63;
  const int w    = tid >> 6;
  const int m    = lane & 15;
  const int quad = lane >> 4;

  // ---- issue all 32 x loads first (independent of LDS staging) ----
  const float* xb = x + (size_t)b * CIN_ * N_ + n0 + 16 * w + m;
  float xf[32];
#pragma unroll
  for (int s = 0; s < 4; ++s)
#pragma unroll
    for (int j = 0; j < 8; ++j)
      xf[8 * s + j] = xb[(size_t)(32 * s + 8 * quad + j) * N_];

  // ---- stage W -> bf16 LDS (coalesced float4 reads, b64 LDS writes) ----
#pragma unroll
  for (int r = 0; r < 16; ++r) {
    int id = tid + 256 * r;   // 0..4095 float4s
    int co = id >> 5;
    int cq = id & 31;         // float4 index along ci
    float4 v = reinterpret_cast<const float4*>(W)[id];
    unsigned p0 = (unsigned)f2bf(v.x) | ((unsigned)f2bf(v.y) << 16);
    unsigned p1 = (unsigned)f2bf(v.z) | ((unsigned)f2bf(v.w) << 16);
    *reinterpret_cast<uint2*>(&Wl[co * 136 + 4 * cq]) = make_uint2(p0, p1);
  }

  // ---- convert x to A-fragments while staging stores drain ----
  bf16x8 a[4];
#pragma unroll
  for (int s = 0; s < 4; ++s)
#pragma unroll
    for (int j = 0; j < 8; ++j)
      a[s][j] = (short)f2bf(xf[8 * s + j]);

  __syncthreads();

  const int rbase = n0 + 16 * w + 4 * quad;
  unsigned short* hb = h + (size_t)b * N_ * COUT_;
#pragma unroll
  for (int t = 0; t < 8; ++t) {   // 8 co-tiles of 16
    f32x4 c = {0.f, 0.f, 0.f, 0.f};
#pragma unroll
    for (int s = 0; s < 4; ++s) { // K = 4 x 32
      bf16x8 bf = *reinterpret_cast<const bf16x8*>(
          &Wl[(16 * t + m) * 136 + 32 * s + 8 * quad]);
      c = __builtin_amdgcn_mfma_f32_16x16x32_bf16(a[s], bf, c, 0, 0, 0);
    }
    int co = 16 * t + m;
#pragma unroll
    for (int r = 0; r < 4; ++r) {
      float v = c[r] > 0.f ? c[r] : 0.f;  // ReLU
      hb[(size_t)(rbase + r) * COUT_ + co] = f2bf(v);
    }
  }
}

// ---------------------------------------------------------------------------
// Kernel 2: out[b][co][n] = (sum_{17} h[b][idx'][:])/17 + bias, idx' incl self
// 2048 blocks x 256 thr; tile 32n x 128co; same XCD mapping as gemm.
// q=tid&15 -> 8 co (16B gather: 16 lanes = one 256B h row), g=tid>>4 -> 2 n.
// launch_bounds(256,8): ~45 VGPR -> 8 waves/SIMD; full k unroll for MLP.
// ---------------------------------------------------------------------------
__global__ __launch_bounds__(256, 8) void aggr_k(
    const unsigned short* __restrict__ h, const int* __restrict__ ei,
    const float* __restrict__ bias, float* __restrict__ out) {
  __shared__ int idx_t[17 * 32];  // [k][n], k=16 is the self loop
  const int tid  = threadIdx.x;
  const int l    = blockIdx.x;
  const int rest = l >> 3;                        // 0..255
  const int b    = ((l & 7) << 1) | (rest >> 7);
  const int n0   = (rest & 127) * 32;

  if (tid < 128) {  // stage+transpose neighbor indices (coalesced int4, NT)
    int n  = tid >> 2;       // 0..31
    int kq = tid & 3;        // int4 along k
    i32x4 v = __builtin_nontemporal_load(
        reinterpret_cast<const i32x4*>(ei + ((size_t)b * N_ + n0 + n) * K_) + kq);
    idx_t[(4 * kq + 0) * 32 + n] = v.x;
    idx_t[(4 * kq + 1) * 32 + n] = v.y;
    idx_t[(4 * kq + 2) * 32 + n] = v.z;
    idx_t[(4 * kq + 3) * 32 + n] = v.w;
    if (tid < 32) idx_t[16 * 32 + tid] = n0 + tid;  // self loop
  }
  __syncthreads();

  const int q = tid & 15;   // co = 8q..8q+7
  const int g = tid >> 4;   // n_local = 2g, 2g+1
  const unsigned short* hb = h + (size_t)b * N_ * COUT_;

  float acc[2][8];
#pragma unroll
  for (int j = 0; j < 2; ++j)
#pragma unroll
    for (int c = 0; c < 8; ++c) acc[j][c] = 0.f;

#pragma unroll
  for (int k = 0; k < 17; ++k) {
    uint4 v[2];
#pragma unroll
    for (int j = 0; j < 2; ++j) {
      int node = idx_t[k * 32 + 2 * g + j];
      v[j] = *reinterpret_cast<const uint4*>(hb + (size_t)node * COUT_ + 8 * q);
    }
#pragma unroll
    for (int j = 0; j < 2; ++j) {
      acc[j][0] += __uint_as_float(v[j].x << 16);
      acc[j][1] += __uint_as_float(v[j].x & 0xffff0000u);
      acc[j][2] += __uint_as_float(v[j].y << 16);
      acc[j][3] += __uint_as_float(v[j].y & 0xffff0000u);
      acc[j][4] += __uint_as_float(v[j].z << 16);
      acc[j][5] += __uint_as_float(v[j].z & 0xffff0000u);
      acc[j][6] += __uint_as_float(v[j].w << 16);
      acc[j][7] += __uint_as_float(v[j].w & 0xffff0000u);
    }
  }

  // bias loaded after the k-loop to keep its registers out of the hot loop
  const float norm = 1.0f / 17.0f;
  const float4 bv0 = *reinterpret_cast<const float4*>(bias + 8 * q);
  const float4 bv1 = *reinterpret_cast<const float4*>(bias + 8 * q + 4);
  float* ob = out + (size_t)b * COUT_ * N_ + n0 + 2 * g;
#pragma unroll
  for (int c = 0; c < 8; ++c) {
    int co = 8 * q + c;
    float bb = (c < 4) ? ((c == 0) ? bv0.x : (c == 1) ? bv0.y : (c == 2) ? bv0.z : bv0.w)
                       : ((c == 4) ? bv1.x : (c == 5) ? bv1.y : (c == 6) ? bv1.z : bv1.w);
    float2 r;
    r.x = acc[0][c] * norm + bb;
    r.y = acc[1][c] * norm + bb;
    *reinterpret_cast<float2*>(ob + (size_t)co * N_) = r;
  }
}

extern "C" void kernel_launch(void* const* d_in, const int* in_sizes, int n_in,
                              void* d_out, int out_size, void* d_ws, size_t ws_size,
                              hipStream_t stream) {
  const float* x    = (const float*)d_in[0];
  const int*   ei   = (const int*)d_in[1];   // [2][B][N][K]; plane 0
  const float* W    = (const float*)d_in[2];
  const float* bias = (const float*)d_in[3];
  float* out = (float*)d_out;
  unsigned short* h = (unsigned short*)d_ws;  // B*N*COUT*2 = 16 MB bf16

  gemm_relu_k<<<dim3(B_ * N_ / 64), 256, 0, stream>>>(x, W, h);
  aggr_k<<<dim3(B_ * N_ / 32), 256, 0, stream>>>(h, ei, bias, out);
}

// Round 8
// 124.141 us; speedup vs baseline: 2.5477x; 2.5477x over previous
//
#include <hip/hip_runtime.h>

#define B_    16
#define CIN_  128
#define COUT_ 128
#define N_    4096
#define K_    16

typedef __attribute__((ext_vector_type(8))) short bf16x8;  // 8 bf16 = 4 VGPR
typedef __attribute__((ext_vector_type(4))) float f32x4;
typedef __attribute__((ext_vector_type(4))) int   i32x4;

__device__ inline unsigned short f2bf(float f) {  // round-to-nearest-even
  unsigned u = __float_as_uint(f);
  u += 0x7fffu + ((u >> 16) & 1u);
  return (unsigned short)(u >> 16);
}

// XCD-affinity: dispatch is round-robin over 8 XCDs by linear block id, so
// batch b is pinned to XCD b>>1 in BOTH kernels -> gemm produces h[b] into the
// same XCD L2 (4 MB = two 2 MB bf16 slabs) that aggr gathers from.
// ---------------------------------------------------------------------------
// Kernel 1: h[b][n][co] = bf16(relu(sum_ci W[co][ci]*x[b][ci][n]))
// 1024 blocks x 256 thr; tile 64n x 128co, full K=128; wave w owns 16 n.
// x loads issued FIRST so HBM traffic overlaps the W staging + convert.
// ---------------------------------------------------------------------------
__global__ __launch_bounds__(256, 4) void gemm_relu_k(
    const float* __restrict__ x, const float* __restrict__ W,
    unsigned short* __restrict__ h) {
  __shared__ unsigned short Wl[128 * 136];  // [co][ci], +8 pad
  const int tid = threadIdx.x;
  const int l   = blockIdx.x;
  const int b   = ((l & 7) << 1) | ((l >> 3) >> 6);
  const int n0  = ((l >> 3) & 63) * 64;

  const int lane = tid & 63;
  const int w    = tid >> 6;
  const int m    = lane & 15;
  const int quad = lane >> 4;

  // ---- issue all 32 x loads first (independent of LDS staging) ----
  const float* xb = x + (size_t)b * CIN_ * N_ + n0 + 16 * w + m;
  float xf[32];
#pragma unroll
  for (int s = 0; s < 4; ++s)
#pragma unroll
    for (int j = 0; j < 8; ++j)
      xf[8 * s + j] = xb[(size_t)(32 * s + 8 * quad + j) * N_];

  // ---- stage W -> bf16 LDS (coalesced float4 reads, b64 LDS writes) ----
#pragma unroll
  for (int r = 0; r < 16; ++r) {
    int id = tid + 256 * r;   // 0..4095 float4s
    int co = id >> 5;
    int cq = id & 31;         // float4 index along ci
    float4 v = reinterpret_cast<const float4*>(W)[id];
    unsigned p0 = (unsigned)f2bf(v.x) | ((unsigned)f2bf(v.y) << 16);
    unsigned p1 = (unsigned)f2bf(v.z) | ((unsigned)f2bf(v.w) << 16);
    *reinterpret_cast<uint2*>(&Wl[co * 136 + 4 * cq]) = make_uint2(p0, p1);
  }

  // ---- convert x to A-fragments while staging stores drain ----
  bf16x8 a[4];
#pragma unroll
  for (int s = 0; s < 4; ++s)
#pragma unroll
    for (int j = 0; j < 8; ++j)
      a[s][j] = (short)f2bf(xf[8 * s + j]);

  __syncthreads();

  const int rbase = n0 + 16 * w + 4 * quad;
  unsigned short* hb = h + (size_t)b * N_ * COUT_;
#pragma unroll
  for (int t = 0; t < 8; ++t) {   // 8 co-tiles of 16
    f32x4 c = {0.f, 0.f, 0.f, 0.f};
#pragma unroll
    for (int s = 0; s < 4; ++s) { // K = 4 x 32
      bf16x8 bf = *reinterpret_cast<const bf16x8*>(
          &Wl[(16 * t + m) * 136 + 32 * s + 8 * quad]);
      c = __builtin_amdgcn_mfma_f32_16x16x32_bf16(a[s], bf, c, 0, 0, 0);
    }
    int co = 16 * t + m;
#pragma unroll
    for (int r = 0; r < 4; ++r) {
      float v = c[r] > 0.f ? c[r] : 0.f;  // ReLU
      hb[(size_t)(rbase + r) * COUT_ + co] = f2bf(v);
    }
  }
}

// ---------------------------------------------------------------------------
// Kernel 2: out[b][co][n] = (sum_{17} h[b][idx'][:])/17 + bias, idx' incl self
// 2048 blocks x 256 thr (8 blocks/CU); tile 32n x 128co; same XCD mapping.
// q=tid&15 -> 8 co (16B gather: 16 lanes = one 256B h row), g=tid>>4 -> 2 n.
// launch_bounds(256,4): 128-VGPR cap -> NO spill (R7's (256,8) forced 64-cap,
// spilled acc to scratch: WRITE 391 MB). Compiler lands ~48-56 VGPR -> 8
// waves/SIMD achievable with 8 resident blocks.
// ---------------------------------------------------------------------------
__global__ __launch_bounds__(256, 4) void aggr_k(
    const unsigned short* __restrict__ h, const int* __restrict__ ei,
    const float* __restrict__ bias, float* __restrict__ out) {
  __shared__ int idx_t[17 * 32];  // [k][n], k=16 is the self loop
  const int tid  = threadIdx.x;
  const int l    = blockIdx.x;
  const int rest = l >> 3;                        // 0..255
  const int b    = ((l & 7) << 1) | (rest >> 7);
  const int n0   = (rest & 127) * 32;

  if (tid < 128) {  // stage+transpose neighbor indices (coalesced int4, NT)
    int n  = tid >> 2;       // 0..31
    int kq = tid & 3;        // int4 along k
    i32x4 v = __builtin_nontemporal_load(
        reinterpret_cast<const i32x4*>(ei + ((size_t)b * N_ + n0 + n) * K_) + kq);
    idx_t[(4 * kq + 0) * 32 + n] = v.x;
    idx_t[(4 * kq + 1) * 32 + n] = v.y;
    idx_t[(4 * kq + 2) * 32 + n] = v.z;
    idx_t[(4 * kq + 3) * 32 + n] = v.w;
    if (tid < 32) idx_t[16 * 32 + tid] = n0 + tid;  // self loop
  }
  __syncthreads();

  const int q = tid & 15;   // co = 8q..8q+7
  const int g = tid >> 4;   // n_local = 2g, 2g+1
  const unsigned short* hb = h + (size_t)b * N_ * COUT_;

  float acc[2][8];
#pragma unroll
  for (int j = 0; j < 2; ++j)
#pragma unroll
    for (int c = 0; c < 8; ++c) acc[j][c] = 0.f;

#pragma unroll 4
  for (int k = 0; k < 17; ++k) {
    uint4 v[2];
#pragma unroll
    for (int j = 0; j < 2; ++j) {
      int node = idx_t[k * 32 + 2 * g + j];
      v[j] = *reinterpret_cast<const uint4*>(hb + (size_t)node * COUT_ + 8 * q);
    }
#pragma unroll
    for (int j = 0; j < 2; ++j) {
      acc[j][0] += __uint_as_float(v[j].x << 16);
      acc[j][1] += __uint_as_float(v[j].x & 0xffff0000u);
      acc[j][2] += __uint_as_float(v[j].y << 16);
      acc[j][3] += __uint_as_float(v[j].y & 0xffff0000u);
      acc[j][4] += __uint_as_float(v[j].z << 16);
      acc[j][5] += __uint_as_float(v[j].z & 0xffff0000u);
      acc[j][6] += __uint_as_float(v[j].w << 16);
      acc[j][7] += __uint_as_float(v[j].w & 0xffff0000u);
    }
  }

  // bias loaded after the k-loop to keep its registers out of the hot loop
  const float norm = 1.0f / 17.0f;
  const float4 bv0 = *reinterpret_cast<const float4*>(bias + 8 * q);
  const float4 bv1 = *reinterpret_cast<const float4*>(bias + 8 * q + 4);
  float* ob = out + (size_t)b * COUT_ * N_ + n0 + 2 * g;
#pragma unroll
  for (int c = 0; c < 8; ++c) {
    int co = 8 * q + c;
    float bb = (c < 4) ? ((c == 0) ? bv0.x : (c == 1) ? bv0.y : (c == 2) ? bv0.z : bv0.w)
                       : ((c == 4) ? bv1.x : (c == 5) ? bv1.y : (c == 6) ? bv1.z : bv1.w);
    float2 r;
    r.x = acc[0][c] * norm + bb;
    r.y = acc[1][c] * norm + bb;
    *reinterpret_cast<float2*>(ob + (size_t)co * N_) = r;
  }
}

extern "C" void kernel_launch(void* const* d_in, const int* in_sizes, int n_in,
                              void* d_out, int out_size, void* d_ws, size_t ws_size,
                              hipStream_t stream) {
  const float* x    = (const float*)d_in[0];
  const int*   ei   = (const int*)d_in[1];   // [2][B][N][K]; plane 0
  const float* W    = (const float*)d_in[2];
  const float* bias = (const float*)d_in[3];
  float* out = (float*)d_out;
  unsigned short* h = (unsigned short*)d_ws;  // B*N*COUT*2 = 16 MB bf16

  gemm_relu_k<<<dim3(B_ * N_ / 64), 256, 0, stream>>>(x, W, h);
  aggr_k<<<dim3(B_ * N_ / 32), 256, 0, stream>>>(h, ei, bias, out);
}

// Round 9
// 116.911 us; speedup vs baseline: 2.7053x; 1.0618x over previous
//
#include <hip/hip_runtime.h>

#define B_    16
#define CIN_  128
#define COUT_ 128
#define N_    4096
#define K_    16

typedef __attribute__((ext_vector_type(8))) short bf16x8;  // 8 bf16 = 4 VGPR
typedef __attribute__((ext_vector_type(4))) float f32x4;
typedef __attribute__((ext_vector_type(4))) int   i32x4;

__device__ inline unsigned short f2bf(float f) {  // round-to-nearest-even
  unsigned u = __float_as_uint(f);
  u += 0x7fffu + ((u >> 16) & 1u);
  return (unsigned short)(u >> 16);
}

// ---------------------------------------------------------------------------
// Kernel 0: one-shot W fp32 -> bf16 conversion into d_ws (32 KB).
// Removes the per-block convert (R6: 1024 blocks x 250 VALU/thread redundant).
// ---------------------------------------------------------------------------
__global__ __launch_bounds__(256) void convW_k(
    const float* __restrict__ W, unsigned short* __restrict__ Wbf) {
  int id = blockIdx.x * 256 + threadIdx.x;   // 4096 float4s
  float4 v = reinterpret_cast<const float4*>(W)[id];
  unsigned p0 = (unsigned)f2bf(v.x) | ((unsigned)f2bf(v.y) << 16);
  unsigned p1 = (unsigned)f2bf(v.z) | ((unsigned)f2bf(v.w) << 16);
  *reinterpret_cast<uint2*>(Wbf + 4 * id) = make_uint2(p0, p1);
}

// XCD-affinity: dispatch is round-robin over 8 XCDs by linear block id, so
// batch b is pinned to XCD b>>1 in BOTH kernels -> gemm produces h[b] into the
// same XCD L2 (4 MB = two 2 MB bf16 slabs) that aggr gathers from.
// ---------------------------------------------------------------------------
// Kernel 1: h[b][n][co] = bf16(relu(sum_ci W[co][ci]*x[b][ci][n]))
// 1024 blocks x 256 thr; tile 64n x 128co, full K=128; wave w owns 16 n.
// W staged from pre-converted bf16: 8 dwordx4 loads + b128 LDS writes/thread.
// ---------------------------------------------------------------------------
__global__ __launch_bounds__(256) void gemm_relu_k(
    const unsigned short* __restrict__ Wbf, const float* __restrict__ x,
    unsigned short* __restrict__ h) {
  __shared__ unsigned short Wl[128 * 136];  // [co][ci], +8 pad
  const int tid = threadIdx.x;
  const int l   = blockIdx.x;
  const int b   = ((l & 7) << 1) | ((l >> 3) >> 6);
  const int n0  = ((l >> 3) & 63) * 64;

  // ---- stage bf16 W -> LDS (16B loads, 16B LDS writes, conflict-free) ----
#pragma unroll
  for (int r = 0; r < 8; ++r) {
    int id  = tid + 256 * r;   // 0..2047 16B-segments
    int co  = id >> 4;         // 0..127
    int seg = id & 15;         // 8-bf16 segment along ci
    uint4 v = reinterpret_cast<const uint4*>(Wbf)[id];
    *reinterpret_cast<uint4*>(&Wl[co * 136 + 8 * seg]) = v;
  }
  __syncthreads();

  const int lane = tid & 63;
  const int w    = tid >> 6;
  const int m    = lane & 15;
  const int quad = lane >> 4;

  // ---- A-fragments straight from global ----
  const float* xb = x + (size_t)b * CIN_ * N_ + n0 + 16 * w + m;
  bf16x8 a[4];
#pragma unroll
  for (int s = 0; s < 4; ++s) {
#pragma unroll
    for (int j = 0; j < 8; ++j) {
      int ci = 32 * s + 8 * quad + j;
      a[s][j] = (short)f2bf(xb[(size_t)ci * N_]);
    }
  }

  const int rbase = n0 + 16 * w + 4 * quad;
  unsigned short* hb = h + (size_t)b * N_ * COUT_;
#pragma unroll
  for (int t = 0; t < 8; ++t) {   // 8 co-tiles of 16
    f32x4 c = {0.f, 0.f, 0.f, 0.f};
#pragma unroll
    for (int s = 0; s < 4; ++s) { // K = 4 x 32
      bf16x8 bf = *reinterpret_cast<const bf16x8*>(
          &Wl[(16 * t + m) * 136 + 32 * s + 8 * quad]);
      c = __builtin_amdgcn_mfma_f32_16x16x32_bf16(a[s], bf, c, 0, 0, 0);
    }
    int co = 16 * t + m;
#pragma unroll
    for (int r = 0; r < 4; ++r) {
      float v = c[r] > 0.f ? c[r] : 0.f;  // ReLU
      hb[(size_t)(rbase + r) * COUT_ + co] = f2bf(v);
    }
  }
}

// ---------------------------------------------------------------------------
// Kernel 2: out[b][co][n] = (sum_{17} h[b][idx'][:])/17 + bias, idx' incl self
// EXACT R6 configuration (best measured): 1024 blocks x 256 thr; tile
// 64n x 128co; q=tid&15 -> 8 co (16B gather: 16 lanes = one 256B h row),
// g=tid>>4 -> 4 n; unroll-2 over k; launch_bounds(256,4) -> no spill.
// ---------------------------------------------------------------------------
__global__ __launch_bounds__(256, 4) void aggr_k(
    const unsigned short* __restrict__ h, const int* __restrict__ ei,
    const float* __restrict__ bias, float* __restrict__ out) {
  __shared__ int idx_t[17 * 64];  // [k][n], k=16 is the self loop
  const int tid  = threadIdx.x;
  const int l    = blockIdx.x;
  const int rest = l >> 3;                        // 0..127
  const int b    = ((l & 7) << 1) | (rest >> 6);
  const int n0   = (rest & 63) * 64;

  {  // stage+transpose neighbor indices (coalesced int4, NT to spare L2)
    int n  = tid >> 2;       // 0..63
    int kq = tid & 3;        // int4 along k
    i32x4 v = __builtin_nontemporal_load(
        reinterpret_cast<const i32x4*>(ei + ((size_t)b * N_ + n0 + n) * K_) + kq);
    idx_t[(4 * kq + 0) * 64 + n] = v.x;
    idx_t[(4 * kq + 1) * 64 + n] = v.y;
    idx_t[(4 * kq + 2) * 64 + n] = v.z;
    idx_t[(4 * kq + 3) * 64 + n] = v.w;
    if (tid < 64) idx_t[16 * 64 + tid] = n0 + tid;  // self loop
  }
  __syncthreads();

  const int q = tid & 15;   // co = 8q..8q+7
  const int g = tid >> 4;   // n_local = 4g .. 4g+3
  const unsigned short* hb = h + (size_t)b * N_ * COUT_;

  float acc[4][8];
#pragma unroll
  for (int j = 0; j < 4; ++j)
#pragma unroll
    for (int c = 0; c < 8; ++c) acc[j][c] = 0.f;

#pragma unroll 2
  for (int k = 0; k < 17; ++k) {
    uint4 v[4];
#pragma unroll
    for (int j = 0; j < 4; ++j) {
      int node = idx_t[k * 64 + 4 * g + j];
      v[j] = *reinterpret_cast<const uint4*>(hb + (size_t)node * COUT_ + 8 * q);
    }
#pragma unroll
    for (int j = 0; j < 4; ++j) {
      acc[j][0] += __uint_as_float(v[j].x << 16);
      acc[j][1] += __uint_as_float(v[j].x & 0xffff0000u);
      acc[j][2] += __uint_as_float(v[j].y << 16);
      acc[j][3] += __uint_as_float(v[j].y & 0xffff0000u);
      acc[j][4] += __uint_as_float(v[j].z << 16);
      acc[j][5] += __uint_as_float(v[j].z & 0xffff0000u);
      acc[j][6] += __uint_as_float(v[j].w << 16);
      acc[j][7] += __uint_as_float(v[j].w & 0xffff0000u);
    }
  }

  const float norm = 1.0f / 17.0f;
  const float4 bv0 = *reinterpret_cast<const float4*>(bias + 8 * q);
  const float4 bv1 = *reinterpret_cast<const float4*>(bias + 8 * q + 4);
  float* ob = out + (size_t)b * COUT_ * N_ + n0 + 4 * g;
#pragma unroll
  for (int c = 0; c < 8; ++c) {
    int co = 8 * q + c;
    float bb = (c < 4) ? ((c == 0) ? bv0.x : (c == 1) ? bv0.y : (c == 2) ? bv0.z : bv0.w)
                       : ((c == 4) ? bv1.x : (c == 5) ? bv1.y : (c == 6) ? bv1.z : bv1.w);
    float4 r;
    r.x = acc[0][c] * norm + bb;
    r.y = acc[1][c] * norm + bb;
    r.z = acc[2][c] * norm + bb;
    r.w = acc[3][c] * norm + bb;
    *reinterpret_cast<float4*>(ob + (size_t)co * N_) = r;  // 16B, 64B/segment
  }
}

extern "C" void kernel_launch(void* const* d_in, const int* in_sizes, int n_in,
                              void* d_out, int out_size, void* d_ws, size_t ws_size,
                              hipStream_t stream) {
  const float* x    = (const float*)d_in[0];
  const int*   ei   = (const int*)d_in[1];   // [2][B][N][K]; plane 0
  const float* W    = (const float*)d_in[2];
  const float* bias = (const float*)d_in[3];
  float* out = (float*)d_out;
  unsigned short* h   = (unsigned short*)d_ws;                      // 16 MB
  unsigned short* Wbf = (unsigned short*)((char*)d_ws + (size_t)B_ * N_ * COUT_ * 2);

  convW_k<<<dim3(16), 256, 0, stream>>>(W, Wbf);
  gemm_relu_k<<<dim3(B_ * N_ / 64), 256, 0, stream>>>(Wbf, x, h);
  aggr_k<<<dim3(B_ * N_ / 64), 256, 0, stream>>>(h, ei, bias, out);
}

// Round 10
// 112.520 us; speedup vs baseline: 2.8108x; 1.0390x over previous
//
#include <hip/hip_runtime.h>

#define B_    16
#define CIN_  128
#define COUT_ 128
#define N_    4096
#define K_    16

typedef __attribute__((ext_vector_type(8))) short bf16x8;  // 8 bf16 = 4 VGPR
typedef __attribute__((ext_vector_type(4))) float f32x4;
typedef __attribute__((ext_vector_type(4))) int   i32x4;

__device__ inline unsigned short f2bf(float f) {  // round-to-nearest-even
  unsigned u = __float_as_uint(f);
  u += 0x7fffu + ((u >> 16) & 1u);
  return (unsigned short)(u >> 16);
}

// ---------------------------------------------------------------------------
// Kernel 0: one-shot W fp32 -> bf16 conversion into d_ws (32 KB).
// ---------------------------------------------------------------------------
__global__ __launch_bounds__(256) void convW_k(
    const float* __restrict__ W, unsigned short* __restrict__ Wbf) {
  int id = blockIdx.x * 256 + threadIdx.x;   // 4096 float4s
  float4 v = reinterpret_cast<const float4*>(W)[id];
  unsigned p0 = (unsigned)f2bf(v.x) | ((unsigned)f2bf(v.y) << 16);
  unsigned p1 = (unsigned)f2bf(v.z) | ((unsigned)f2bf(v.w) << 16);
  *reinterpret_cast<uint2*>(Wbf + 4 * id) = make_uint2(p0, p1);
}

// XCD-affinity: dispatch is round-robin over 8 XCDs by linear block id, so
// batch b is pinned to XCD b>>1 in BOTH kernels -> gemm produces h[b] into the
// same XCD L2 (4 MB = two 2 MB bf16 slabs) that aggr gathers from.
// ---------------------------------------------------------------------------
// Kernel 1: h[b][n][co] = bf16(relu(sum_ci W[co][ci]*x[b][ci][n]))
// 256 blocks x 1024 thr (1 block/CU, 16 waves); tile 256n x 128co.
// W staged ONCE per 256 n (4x amortization vs R9). Epilogue transposes C
// through padded LDS -> dwordx4 stores (1 KB/wave-instr vs R9's 32 B segs).
// ---------------------------------------------------------------------------
__global__ __launch_bounds__(1024, 4) void gemm_relu_k(
    const unsigned short* __restrict__ Wbf, const float* __restrict__ x,
    unsigned short* __restrict__ h) {
  __shared__ unsigned short Wl[128 * 136];   // [co][ci], +8 pad (34.8 KB)
  __shared__ unsigned short He[256 * 144];   // [n][co], +16 pad (73.7 KB)
  const int tid  = threadIdx.x;
  const int l    = blockIdx.x;          // 0..255
  const int slot = l >> 3;              // 0..31
  const int b    = ((l & 7) << 1) | (slot >> 4);
  const int n0   = (slot & 15) * 256;

  // ---- stage bf16 W -> LDS (2 x 16B per thread, conflict-free) ----
#pragma unroll
  for (int r = 0; r < 2; ++r) {
    int id  = tid + 1024 * r;   // 0..2047 16B-segments
    int co  = id >> 4;          // 0..127
    int seg = id & 15;          // 8-bf16 segment along ci
    uint4 v = reinterpret_cast<const uint4*>(Wbf)[id];
    *reinterpret_cast<uint4*>(&Wl[co * 136 + 8 * seg]) = v;
  }
  __syncthreads();

  const int lane = tid & 63;
  const int w    = tid >> 6;    // wave 0..15 -> n slice [n0+16w, +16)
  const int m    = lane & 15;
  const int quad = lane >> 4;

  // ---- A-fragments straight from global ----
  const float* xb = x + (size_t)b * CIN_ * N_ + n0 + 16 * w + m;
  bf16x8 a[4];
#pragma unroll
  for (int s = 0; s < 4; ++s)
#pragma unroll
    for (int j = 0; j < 8; ++j)
      a[s][j] = (short)f2bf(xb[(size_t)(32 * s + 8 * quad + j) * N_]);

  const int nrow = 16 * w + 4 * quad;   // block-local n of c[0]
#pragma unroll
  for (int t = 0; t < 8; ++t) {   // 8 co-tiles of 16
    f32x4 c = {0.f, 0.f, 0.f, 0.f};
#pragma unroll
    for (int s = 0; s < 4; ++s) { // K = 4 x 32
      bf16x8 bf = *reinterpret_cast<const bf16x8*>(
          &Wl[(16 * t + m) * 136 + 32 * s + 8 * quad]);
      c = __builtin_amdgcn_mfma_f32_16x16x32_bf16(a[s], bf, c, 0, 0, 0);
    }
    int co = 16 * t + m;
#pragma unroll
    for (int r = 0; r < 4; ++r) {
      float v = c[r] > 0.f ? c[r] : 0.f;  // ReLU
      He[(nrow + r) * 144 + co] = f2bf(v);  // pad 144: quads hit distinct banks
    }
  }
  __syncthreads();

  // ---- vectorized store: 4 x dwordx4/thread, 1 KB contiguous per wave ----
  unsigned short* hb = h + ((size_t)b * N_ + n0) * COUT_;
  const int seg = tid & 15;
  const int nr  = tid >> 4;   // 0..63
#pragma unroll
  for (int p = 0; p < 4; ++p) {
    int n = nr + 64 * p;
    uint4 v = *reinterpret_cast<const uint4*>(&He[n * 144 + 8 * seg]);
    *reinterpret_cast<uint4*>(hb + (size_t)n * COUT_ + 8 * seg) = v;
  }
}

// ---------------------------------------------------------------------------
// Kernel 2: out[b][co][n] = (sum_{17} h[b][idx'][:])/17 + bias, idx' incl self
// EXACT R9/R6 configuration (best measured): 1024 blocks x 256 thr; tile
// 64n x 128co; q=tid&15 -> 8 co (16B gather: 16 lanes = one 256B h row),
// g=tid>>4 -> 4 n; unroll-2 over k; launch_bounds(256,4) -> no spill.
// ---------------------------------------------------------------------------
__global__ __launch_bounds__(256, 4) void aggr_k(
    const unsigned short* __restrict__ h, const int* __restrict__ ei,
    const float* __restrict__ bias, float* __restrict__ out) {
  __shared__ int idx_t[17 * 64];  // [k][n], k=16 is the self loop
  const int tid  = threadIdx.x;
  const int l    = blockIdx.x;
  const int rest = l >> 3;                        // 0..127
  const int b    = ((l & 7) << 1) | (rest >> 6);
  const int n0   = (rest & 63) * 64;

  {  // stage+transpose neighbor indices (coalesced int4, NT to spare L2)
    int n  = tid >> 2;       // 0..63
    int kq = tid & 3;        // int4 along k
    i32x4 v = __builtin_nontemporal_load(
        reinterpret_cast<const i32x4*>(ei + ((size_t)b * N_ + n0 + n) * K_) + kq);
    idx_t[(4 * kq + 0) * 64 + n] = v.x;
    idx_t[(4 * kq + 1) * 64 + n] = v.y;
    idx_t[(4 * kq + 2) * 64 + n] = v.z;
    idx_t[(4 * kq + 3) * 64 + n] = v.w;
    if (tid < 64) idx_t[16 * 64 + tid] = n0 + tid;  // self loop
  }
  __syncthreads();

  const int q = tid & 15;   // co = 8q..8q+7
  const int g = tid >> 4;   // n_local = 4g .. 4g+3
  const unsigned short* hb = h + (size_t)b * N_ * COUT_;

  float acc[4][8];
#pragma unroll
  for (int j = 0; j < 4; ++j)
#pragma unroll
    for (int c = 0; c < 8; ++c) acc[j][c] = 0.f;

#pragma unroll 2
  for (int k = 0; k < 17; ++k) {
    uint4 v[4];
#pragma unroll
    for (int j = 0; j < 4; ++j) {
      int node = idx_t[k * 64 + 4 * g + j];
      v[j] = *reinterpret_cast<const uint4*>(hb + (size_t)node * COUT_ + 8 * q);
    }
#pragma unroll
    for (int j = 0; j < 4; ++j) {
      acc[j][0] += __uint_as_float(v[j].x << 16);
      acc[j][1] += __uint_as_float(v[j].x & 0xffff0000u);
      acc[j][2] += __uint_as_float(v[j].y << 16);
      acc[j][3] += __uint_as_float(v[j].y & 0xffff0000u);
      acc[j][4] += __uint_as_float(v[j].z << 16);
      acc[j][5] += __uint_as_float(v[j].z & 0xffff0000u);
      acc[j][6] += __uint_as_float(v[j].w << 16);
      acc[j][7] += __uint_as_float(v[j].w & 0xffff0000u);
    }
  }

  const float norm = 1.0f / 17.0f;
  const float4 bv0 = *reinterpret_cast<const float4*>(bias + 8 * q);
  const float4 bv1 = *reinterpret_cast<const float4*>(bias + 8 * q + 4);
  float* ob = out + (size_t)b * COUT_ * N_ + n0 + 4 * g;
#pragma unroll
  for (int c = 0; c < 8; ++c) {
    int co = 8 * q + c;
    float bb = (c < 4) ? ((c == 0) ? bv0.x : (c == 1) ? bv0.y : (c == 2) ? bv0.z : bv0.w)
                       : ((c == 4) ? bv1.x : (c == 5) ? bv1.y : (c == 6) ? bv1.z : bv1.w);
    float4 r;
    r.x = acc[0][c] * norm + bb;
    r.y = acc[1][c] * norm + bb;
    r.z = acc[2][c] * norm + bb;
    r.w = acc[3][c] * norm + bb;
    *reinterpret_cast<float4*>(ob + (size_t)co * N_) = r;  // 16B, 64B/segment
  }
}

extern "C" void kernel_launch(void* const* d_in, const int* in_sizes, int n_in,
                              void* d_out, int out_size, void* d_ws, size_t ws_size,
                              hipStream_t stream) {
  const float* x    = (const float*)d_in[0];
  const int*   ei   = (const int*)d_in[1];   // [2][B][N][K]; plane 0
  const float* W    = (const float*)d_in[2];
  const float* bias = (const float*)d_in[3];
  float* out = (float*)d_out;
  unsigned short* h   = (unsigned short*)d_ws;                      // 16 MB
  unsigned short* Wbf = (unsigned short*)((char*)d_ws + (size_t)B_ * N_ * COUT_ * 2);

  convW_k<<<dim3(16), 256, 0, stream>>>(W, Wbf);
  gemm_relu_k<<<dim3(256), 1024, 0, stream>>>(Wbf, x, h);
  aggr_k<<<dim3(B_ * N_ / 64), 256, 0, stream>>>(h, ei, bias, out);
}